// Round 7
// baseline (192.623 us; speedup 1.0000x reference)
//
#include <hip/hip_runtime.h>

#define DIM 64
#define HID 256           // 4*dim
#define ROWB 512          // bytes per node row: [A(256)|B(256)] biased-uint8, perm [m][ct]
#define QSCALE  25.4f     // 127/5  (quantize)
#define DQSCALE (5.0f/127.0f)

typedef short s8v __attribute__((ext_vector_type(8)));   // 8 bf16 (4 VGPRs)
typedef float f4v __attribute__((ext_vector_type(4)));   // 4 fp32 acc

union U16 { uint4 u; s8v s; };

__device__ __forceinline__ unsigned short bf16_rne(float f) {
    unsigned u = __float_as_uint(f);
    u = (u + 0x7fffu + ((u >> 16) & 1u)) >> 16;
    return (unsigned short)u;
}
__device__ __forceinline__ unsigned pk_bf16(float a, float b) {
    return (unsigned)bf16_rne(a) | ((unsigned)bf16_rne(b) << 16);
}

// DPP add; result of 64-lane sum lands in lane 63.
#define DPP_ADD(x, ctrl, rmask)                                               \
    (x) += __int_as_float(__builtin_amdgcn_update_dpp(                        \
        0, __float_as_int(x), (ctrl), (rmask), 0xf, true))
__device__ __forceinline__ float wave_sum64(float x) {
    DPP_ADD(x, 0x111, 0xf);   // row_shr:1
    DPP_ADD(x, 0x112, 0xf);   // row_shr:2
    DPP_ADD(x, 0x114, 0xf);   // row_shr:4
    DPP_ADD(x, 0x118, 0xf);   // row_shr:8
    DPP_ADD(x, 0x142, 0xa);   // row_bcast:15
    DPP_ADD(x, 0x143, 0xc);   // row_bcast:31 -> lane63 = total
    return x;
}

// byte k of u as float (compiles to v_cvt_f32_ubyte{k})
#define UB2F(u, k) ((float)(((u) >> (8 * (k))) & 0xffu))

// ---------------------------------------------------------------------------
// Kernel 0: swizzle Wcat = [W1[0:64,:] | W1[64:128,:]] (64 x 512 fp32) into
// bf16 B-fragments for mfma_f32_16x16x32_bf16 (unchanged).
// ---------------------------------------------------------------------------
__global__ __launch_bounds__(256) void prep_wfrag(
    const float* __restrict__ W1, unsigned short* __restrict__ wf)
{
    const int f = blockIdx.x * 256 + threadIdx.x;
    if (f >= 32 * 2 * 64) return;
    const int lane = f & 63;
    const int t    = (f >> 6) & 1;
    const int ct   = f >> 7;
    const int col  = ct * 16 + (lane & 15);
    const int k0   = t * 32 + (lane >> 4) * 8;
    const float* __restrict__ wsrc =
        W1 + ((col >= HID) ? (DIM * HID + col - HID) : col);
    unsigned short v[8];
#pragma unroll
    for (int j = 0; j < 8; ++j) v[j] = bf16_rne(wsrc[(size_t)(k0 + j) * HID]);
    uint4 o;
    o.x = (unsigned)v[0] | ((unsigned)v[1] << 16);
    o.y = (unsigned)v[2] | ((unsigned)v[3] << 16);
    o.z = (unsigned)v[4] | ((unsigned)v[5] << 16);
    o.w = (unsigned)v[6] | ((unsigned)v[7] << 16);
    *(uint4*)(wf + (size_t)f * 8) = o;
}

// ---------------------------------------------------------------------------
// Kernel 1: MFMA node GEMM -> biased-uint8 table (q+128), permuted [m][ct]
// layout; identical to R6 except the +128 bias in the pack.
// ---------------------------------------------------------------------------
__global__ __launch_bounds__(256) void node_mfma_q(
    const float* __restrict__ x, const unsigned short* __restrict__ wf,
    const float* __restrict__ b1, unsigned char* __restrict__ tab, int n)
{
    const int lane    = threadIdx.x & 63;
    const int w       = threadIdx.x >> 6;
    const int rowgrp  = w >> 1;
    const int colhalf = w & 1;
    const int m       = lane & 15;
    const int quad    = lane >> 4;
    const int rbase   = blockIdx.x * 32 + rowgrp * 16;

    const int arow = rbase + m;
    const float* __restrict__ xr = x + (size_t)((arow < n) ? arow : (n - 1)) * DIM;
    s8v a[2];
#pragma unroll
    for (int t = 0; t < 2; ++t) {
        const float4 lo = *(const float4*)(xr + t * 32 + quad * 8);
        const float4 hi = *(const float4*)(xr + t * 32 + quad * 8 + 4);
        U16 u;
        u.u.x = pk_bf16(lo.x, lo.y);
        u.u.y = pk_bf16(lo.z, lo.w);
        u.u.z = pk_bf16(hi.x, hi.y);
        u.u.w = pk_bf16(hi.z, hi.w);
        a[t] = u.s;
    }

    const uint4* __restrict__ wfv = (const uint4*)wf;

    f4v acc[16];
#pragma unroll
    for (int ct = 0; ct < 16; ++ct) {
        const int ctg = colhalf * 16 + ct;
        U16 b0u, b1u;
        b0u.u = wfv[(ctg * 2 + 0) * 64 + lane];
        b1u.u = wfv[(ctg * 2 + 1) * 64 + lane];
        f4v c = {0.f, 0.f, 0.f, 0.f};
        c = __builtin_amdgcn_mfma_f32_16x16x32_bf16(a[0], b0u.s, c, 0, 0, 0);
        c = __builtin_amdgcn_mfma_f32_16x16x32_bf16(a[1], b1u.s, c, 0, 0, 0);
        if (colhalf == 0) {
            const float bias = b1[ctg * 16 + m];
            c[0] += bias; c[1] += bias; c[2] += bias; c[3] += bias;
        }
        acc[ct] = c;
    }

#pragma unroll
    for (int r = 0; r < 4; ++r) {
        const int gr = rbase + quad * 4 + r;
        if (gr >= n) continue;
        unsigned b[16];
#pragma unroll
        for (int ct = 0; ct < 16; ++ct) {
            float v = __builtin_rintf(acc[ct][r] * QSCALE);
            v = fminf(fmaxf(v, -127.f), 127.f);
            b[ct] = (unsigned)((int)v + 128) & 255u;   // biased: 1..255
        }
        uint4 o;
        o.x = b[0]  | (b[1]  << 8) | (b[2]  << 16) | (b[3]  << 24);
        o.y = b[4]  | (b[5]  << 8) | (b[6]  << 16) | (b[7]  << 24);
        o.z = b[8]  | (b[9]  << 8) | (b[10] << 16) | (b[11] << 24);
        o.w = b[12] | (b[13] << 8) | (b[14] << 16) | (b[15] << 24);
        *(uint4*)(tab + (size_t)gr * ROWB + colhalf * 256 + m * 16) = o;
    }
}

// ---------------------------------------------------------------------------
// Kernel 2: per-edge MLP tail on the biased-uint8 table, [e0v, e1v) range.
// relu identity: max(ua+ub,256)-256 == relu(a+b); the -256 term telescopes to
// a per-wave constant 256*sum(w over wave) computed once. Hot path per element:
// 2x v_cvt_f32_ubyte + add + max(256.0) + fma.
// ---------------------------------------------------------------------------
__global__ __launch_bounds__(256) void edge_mlp_q(
    const int* __restrict__ ei, const unsigned char* __restrict__ tab,
    const float* __restrict__ W2, const float* __restrict__ b2,
    float* __restrict__ out, int ne, int e0v, int e1v)
{
    const int lane = threadIdx.x & 63;
    const int lx   = lane ^ 32;
    const int wid  = blockIdx.x * (blockDim.x >> 6) + (threadIdx.x >> 6);
    const int nw   = gridDim.x * (blockDim.x >> 6);
    const int lp   = lane & 31;
    const int mcol = lp >> 1;            // m of this lane's bytes
    const int ctb  = (lp & 1) * 8;       // ct base of this lane's bytes
    float wv[8];
#pragma unroll
    for (int k = 0; k < 8; ++k) wv[k] = W2[(ctb + k) * 16 + mcol];  // u = ct*16+m
    // per-wave constant: sum over all 64 lanes' 8 w's = 2 * sum(W2)
    float wsum = wv[0] + wv[1] + wv[2] + wv[3] + wv[4] + wv[5] + wv[6] + wv[7];
    wsum = wave_sum64(wsum);             // valid in lane 63 (the storing lane)
    const float bias = b2[0];

    for (int e0 = e0v + wid * 4; e0 < e1v; e0 += nw * 4) {
        const int eu = __builtin_amdgcn_readfirstlane(e0);
        uint2 hs[4], hd[4];
#pragma unroll
        for (int q = 0; q < 4; ++q) {
            const int s = ei[eu + q];
            const int d = ei[ne + eu + q];
            hs[q] = *(const uint2*)(tab + (size_t)s * ROWB + 8 * lane);
            hd[q] = *(const uint2*)(tab + (size_t)d * ROWB + 8 * lx);
        }
        float p[4];
#pragma unroll
        for (int q = 0; q < 4; ++q) {
            float acc = 0.f;
#pragma unroll
            for (int k = 0; k < 4; ++k) {
                const float t = fmaxf(UB2F(hs[q].x, k) + UB2F(hd[q].x, k), 256.0f);
                acc = fmaf(t, wv[k], acc);
            }
#pragma unroll
            for (int k = 0; k < 4; ++k) {
                const float t = fmaxf(UB2F(hs[q].y, k) + UB2F(hd[q].y, k), 256.0f);
                acc = fmaf(t, wv[4 + k], acc);
            }
            p[q] = wave_sum64(acc);      // lane 63: sum incl. +256*wsum excess
        }
        if (lane == 63) {
            const float sc = 0.5f * DQSCALE;
            const float corr = bias - sc * 256.0f * wsum;  // removes telescoped term
            *(float4*)(out + e0) = make_float4(
                sc * p[0] + corr, sc * p[1] + corr,
                sc * p[2] + corr, sc * p[3] + corr);
        }
    }
}

// ---------------------------------------------------------------------------
// Inputs: 0:x[N,64] f32  1:edge_index3[2,E] i32  2,3: edge_attr (unused)
//         4: batch (unused)  5:W1[128,256] 6:b1[256] 7:W2[256,1] 8:b2[1]
// Output: [E] f32.
// Workspace: tab = N*512 uint8 (25.6 MB), then wf = 64 KB W-fragments.
// Edge work split into two half-range dispatches (diagnostic: lets
// node_mfma_q surface in rocprof top-5 if it exceeds ~28 us).
// ---------------------------------------------------------------------------
extern "C" void kernel_launch(void* const* d_in, const int* in_sizes, int n_in,
                              void* d_out, int out_size, void* d_ws, size_t ws_size,
                              hipStream_t stream) {
    const float* x  = (const float*)d_in[0];
    const int*   ei = (const int*)d_in[1];
    const float* W1 = (const float*)d_in[5];
    const float* b1 = (const float*)d_in[6];
    const float* W2 = (const float*)d_in[7];
    const float* b2 = (const float*)d_in[8];
    float* out = (float*)d_out;

    const int n  = in_sizes[0] / DIM;  // 50000 nodes
    const int ne = in_sizes[1] / 2;    // 500000 edges

    unsigned char*  tab = (unsigned char*)d_ws;             // [n,512] uint8
    unsigned short* wf  = (unsigned short*)(tab + (size_t)n * ROWB);

    prep_wfrag<<<16, 256, 0, stream>>>(W1, wf);
    node_mfma_q<<<(n + 31) / 32, 256, 0, stream>>>(x, wf, b1, tab, n);
    const int half = (ne / 2) & ~3;
    edge_mlp_q<<<4096, 256, 0, stream>>>(ei, tab, W2, b2, out, ne, 0, half);
    edge_mlp_q<<<4096, 256, 0, stream>>>(ei, tab, W2, b2, out, ne, half, ne);
}

// Round 8
// 188.072 us; speedup vs baseline: 1.0242x; 1.0242x over previous
//
#include <hip/hip_runtime.h>

#define DIM 64
#define HID 256           // 4*dim
#define ROWB 512          // bytes per node row: [A(256)|B(256)] biased-uint8, perm [m][ct]
#define QSCALE  25.4f     // 127/5  (quantize)
#define DQSCALE (5.0f/127.0f)

typedef short s8v __attribute__((ext_vector_type(8)));   // 8 bf16 (4 VGPRs)
typedef float f4v __attribute__((ext_vector_type(4)));   // 4 fp32 acc

union U16 { uint4 u; s8v s; };

__device__ __forceinline__ unsigned short bf16_rne(float f) {
    unsigned u = __float_as_uint(f);
    u = (u + 0x7fffu + ((u >> 16) & 1u)) >> 16;
    return (unsigned short)u;
}
__device__ __forceinline__ unsigned pk_bf16(float a, float b) {
    return (unsigned)bf16_rne(a) | ((unsigned)bf16_rne(b) << 16);
}

// DPP add; result of 64-lane sum lands in lane 63.
#define DPP_ADD(x, ctrl, rmask)                                               \
    (x) += __int_as_float(__builtin_amdgcn_update_dpp(                        \
        0, __float_as_int(x), (ctrl), (rmask), 0xf, true))
__device__ __forceinline__ float wave_sum64(float x) {
    DPP_ADD(x, 0x111, 0xf);   // row_shr:1
    DPP_ADD(x, 0x112, 0xf);   // row_shr:2
    DPP_ADD(x, 0x114, 0xf);   // row_shr:4
    DPP_ADD(x, 0x118, 0xf);   // row_shr:8
    DPP_ADD(x, 0x142, 0xa);   // row_bcast:15
    DPP_ADD(x, 0x143, 0xc);   // row_bcast:31 -> lane63 = total
    return x;
}

// byte k of u as float (compiles to v_cvt_f32_ubyte{k})
#define UB2F(u, k) ((float)(((u) >> (8 * (k))) & 0xffu))

// ---------------------------------------------------------------------------
// Kernel 0: swizzle Wcat = [W1[0:64,:] | W1[64:128,:]] (64 x 512 fp32) into
// bf16 B-fragments for mfma_f32_16x16x32_bf16.
// ---------------------------------------------------------------------------
__global__ __launch_bounds__(256) void prep_wfrag(
    const float* __restrict__ W1, unsigned short* __restrict__ wf)
{
    const int f = blockIdx.x * 256 + threadIdx.x;
    if (f >= 32 * 2 * 64) return;
    const int lane = f & 63;
    const int t    = (f >> 6) & 1;
    const int ct   = f >> 7;
    const int col  = ct * 16 + (lane & 15);
    const int k0   = t * 32 + (lane >> 4) * 8;
    const float* __restrict__ wsrc =
        W1 + ((col >= HID) ? (DIM * HID + col - HID) : col);
    unsigned short v[8];
#pragma unroll
    for (int j = 0; j < 8; ++j) v[j] = bf16_rne(wsrc[(size_t)(k0 + j) * HID]);
    uint4 o;
    o.x = (unsigned)v[0] | ((unsigned)v[1] << 16);
    o.y = (unsigned)v[2] | ((unsigned)v[3] << 16);
    o.z = (unsigned)v[4] | ((unsigned)v[5] << 16);
    o.w = (unsigned)v[6] | ((unsigned)v[7] << 16);
    *(uint4*)(wf + (size_t)f * 8) = o;
}

// ---------------------------------------------------------------------------
// Kernel 1: MFMA node GEMM -> biased-uint8 table (q+128), permuted [m][ct]
// layout. C-fragment (col=lane&15, row=quad*4+r): lane m's 16 ct-values per
// row are CONTIGUOUS bytes => 4 coalesced dwordx4 stores per wave.
// ---------------------------------------------------------------------------
__global__ __launch_bounds__(256) void node_mfma_q(
    const float* __restrict__ x, const unsigned short* __restrict__ wf,
    const float* __restrict__ b1, unsigned char* __restrict__ tab, int n)
{
    const int lane    = threadIdx.x & 63;
    const int w       = threadIdx.x >> 6;
    const int rowgrp  = w >> 1;
    const int colhalf = w & 1;
    const int m       = lane & 15;
    const int quad    = lane >> 4;
    const int rbase   = blockIdx.x * 32 + rowgrp * 16;

    const int arow = rbase + m;
    const float* __restrict__ xr = x + (size_t)((arow < n) ? arow : (n - 1)) * DIM;
    s8v a[2];
#pragma unroll
    for (int t = 0; t < 2; ++t) {
        const float4 lo = *(const float4*)(xr + t * 32 + quad * 8);
        const float4 hi = *(const float4*)(xr + t * 32 + quad * 8 + 4);
        U16 u;
        u.u.x = pk_bf16(lo.x, lo.y);
        u.u.y = pk_bf16(lo.z, lo.w);
        u.u.z = pk_bf16(hi.x, hi.y);
        u.u.w = pk_bf16(hi.z, hi.w);
        a[t] = u.s;
    }

    const uint4* __restrict__ wfv = (const uint4*)wf;

    f4v acc[16];
#pragma unroll
    for (int ct = 0; ct < 16; ++ct) {
        const int ctg = colhalf * 16 + ct;
        U16 b0u, b1u;
        b0u.u = wfv[(ctg * 2 + 0) * 64 + lane];
        b1u.u = wfv[(ctg * 2 + 1) * 64 + lane];
        f4v c = {0.f, 0.f, 0.f, 0.f};
        c = __builtin_amdgcn_mfma_f32_16x16x32_bf16(a[0], b0u.s, c, 0, 0, 0);
        c = __builtin_amdgcn_mfma_f32_16x16x32_bf16(a[1], b1u.s, c, 0, 0, 0);
        if (colhalf == 0) {
            const float bias = b1[ctg * 16 + m];
            c[0] += bias; c[1] += bias; c[2] += bias; c[3] += bias;
        }
        acc[ct] = c;
    }

#pragma unroll
    for (int r = 0; r < 4; ++r) {
        const int gr = rbase + quad * 4 + r;
        if (gr >= n) continue;
        unsigned b[16];
#pragma unroll
        for (int ct = 0; ct < 16; ++ct) {
            float v = __builtin_rintf(acc[ct][r] * QSCALE);
            v = fminf(fmaxf(v, -127.f), 127.f);
            b[ct] = (unsigned)((int)v + 128) & 255u;   // biased: 1..255
        }
        uint4 o;
        o.x = b[0]  | (b[1]  << 8) | (b[2]  << 16) | (b[3]  << 24);
        o.y = b[4]  | (b[5]  << 8) | (b[6]  << 16) | (b[7]  << 24);
        o.z = b[8]  | (b[9]  << 8) | (b[10] << 16) | (b[11] << 24);
        o.w = b[12] | (b[13] << 8) | (b[14] << 16) | (b[15] << 24);
        *(uint4*)(tab + (size_t)gr * ROWB + colhalf * 256 + m * 16) = o;
    }
}

// ---------------------------------------------------------------------------
// Kernel 2: per-edge MLP tail on the biased-uint8 table (single dispatch).
// Row = 512 B; lane reads 8 B: s at [8*lane], d at [8*(lane^32)] (A/B swap in
// addressing). relu identity: max(ua+ub,256)-256 == relu(a+b); the -256 term
// telescopes to a per-wave constant folded into the output correction.
// Hot path per unit: 2x v_cvt_f32_ubyte + add + max(256.0) + fma.
// ---------------------------------------------------------------------------
__global__ __launch_bounds__(256) void edge_mlp_q(
    const int* __restrict__ ei, const unsigned char* __restrict__ tab,
    const float* __restrict__ W2, const float* __restrict__ b2,
    float* __restrict__ out, int ne)
{
    const int lane = threadIdx.x & 63;
    const int lx   = lane ^ 32;
    const int wid  = blockIdx.x * (blockDim.x >> 6) + (threadIdx.x >> 6);
    const int nw   = gridDim.x * (blockDim.x >> 6);
    const int lp   = lane & 31;
    const int mcol = lp >> 1;            // m of this lane's bytes
    const int ctb  = (lp & 1) * 8;       // ct base of this lane's bytes
    float wv[8];
#pragma unroll
    for (int k = 0; k < 8; ++k) wv[k] = W2[(ctb + k) * 16 + mcol];  // u = ct*16+m
    float wsum = wv[0] + wv[1] + wv[2] + wv[3] + wv[4] + wv[5] + wv[6] + wv[7];
    wsum = wave_sum64(wsum);             // valid in lane 63 (the storing lane)
    const float bias = b2[0];

    for (int e0 = wid * 4; e0 < ne; e0 += nw * 4) {
        const int eu = __builtin_amdgcn_readfirstlane(e0);
        uint2 hs[4], hd[4];
#pragma unroll
        for (int q = 0; q < 4; ++q) {
            const int s = ei[eu + q];
            const int d = ei[ne + eu + q];
            hs[q] = *(const uint2*)(tab + (size_t)s * ROWB + 8 * lane);
            hd[q] = *(const uint2*)(tab + (size_t)d * ROWB + 8 * lx);
        }
        float p[4];
#pragma unroll
        for (int q = 0; q < 4; ++q) {
            float acc = 0.f;
#pragma unroll
            for (int k = 0; k < 4; ++k) {
                const float t = fmaxf(UB2F(hs[q].x, k) + UB2F(hd[q].x, k), 256.0f);
                acc = fmaf(t, wv[k], acc);
            }
#pragma unroll
            for (int k = 0; k < 4; ++k) {
                const float t = fmaxf(UB2F(hs[q].y, k) + UB2F(hd[q].y, k), 256.0f);
                acc = fmaf(t, wv[4 + k], acc);
            }
            p[q] = wave_sum64(acc);      // lane 63: sum incl. +256*wsum excess
        }
        if (lane == 63) {
            const float sc = 0.5f * DQSCALE;
            const float corr = bias - sc * 256.0f * wsum;  // removes telescoped term
            *(float4*)(out + e0) = make_float4(
                sc * p[0] + corr, sc * p[1] + corr,
                sc * p[2] + corr, sc * p[3] + corr);
        }
    }
}

// ---------------------------------------------------------------------------
// Inputs: 0:x[N,64] f32  1:edge_index3[2,E] i32  2,3: edge_attr (unused)
//         4: batch (unused)  5:W1[128,256] 6:b1[256] 7:W2[256,1] 8:b2[1]
// Output: [E] f32.
// Workspace: tab = N*512 uint8 (25.6 MB), then wf = 64 KB W-fragments.
// ---------------------------------------------------------------------------
extern "C" void kernel_launch(void* const* d_in, const int* in_sizes, int n_in,
                              void* d_out, int out_size, void* d_ws, size_t ws_size,
                              hipStream_t stream) {
    const float* x  = (const float*)d_in[0];
    const int*   ei = (const int*)d_in[1];
    const float* W1 = (const float*)d_in[5];
    const float* b1 = (const float*)d_in[6];
    const float* W2 = (const float*)d_in[7];
    const float* b2 = (const float*)d_in[8];
    float* out = (float*)d_out;

    const int n  = in_sizes[0] / DIM;  // 50000 nodes
    const int ne = in_sizes[1] / 2;    // 500000 edges

    unsigned char*  tab = (unsigned char*)d_ws;             // [n,512] uint8
    unsigned short* wf  = (unsigned short*)(tab + (size_t)n * ROWB);

    prep_wfrag<<<16, 256, 0, stream>>>(W1, wf);
    node_mfma_q<<<(n + 31) / 32, 256, 0, stream>>>(x, wf, b1, tab, n);
    edge_mlp_q<<<8192, 256, 0, stream>>>(ei, tab, W2, b2, out, ne);
}